// Round 1
// baseline (17132.610 us; speedup 1.0000x reference)
//
#include <hip/hip_runtime.h>
#include <math.h>

#define Bb 4096
#define Mm 306
#define Nn 984
#define ITERS 50
#define KT 16
#define KSQ 16   // squaring stages: G^(2^16) — robust even for tiny eigen-gap

__device__ __forceinline__ void cmac(float2& c, const float2 a, const float2 b) {
    // c += a*b (complex)
    c.x = fmaf(a.x, b.x, c.x);
    c.x = fmaf(-a.y, b.y, c.x);
    c.y = fmaf(a.x, b.y, c.y);
    c.y = fmaf(a.y, b.x, c.y);
}

// ---------------- G = phi * phi^H  (306x306 complex) ----------------
__global__ void gram_kernel(const float* __restrict__ pr, const float* __restrict__ pi,
                            float2* __restrict__ G) {
    int j = blockIdx.x * 16 + threadIdx.x;
    int i = blockIdx.y * 16 + threadIdx.y;
    if (i >= Mm || j >= Mm) return;
    const float* pri = pr + (size_t)i * Nn;
    const float* pii = pi + (size_t)i * Nn;
    const float* prj = pr + (size_t)j * Nn;
    const float* pij = pi + (size_t)j * Nn;
    float ar = 0.f, ai = 0.f;
    for (int n = 0; n < Nn; ++n) {
        float xr = pri[n], xi = pii[n], yr = prj[n], yi = pij[n];
        // x * conj(y)
        ar = fmaf(xr, yr, ar); ar = fmaf(xi, yi, ar);
        ai = fmaf(xi, yr, ai); ai = fmaf(-xr, yi, ai);
    }
    G[i * Mm + j] = make_float2(ar, ai);
}

// ---------------- Frobenius^2 reduction into slot ----------------
__global__ void frob_kernel(const float2* __restrict__ H, float* __restrict__ slot, int n) {
    int idx = blockIdx.x * blockDim.x + threadIdx.x;
    int stride = gridDim.x * blockDim.x;
    float s = 0.f;
    for (int i = idx; i < n; i += stride) {
        float2 v = H[i];
        s = fmaf(v.x, v.x, s);
        s = fmaf(v.y, v.y, s);
    }
    #pragma unroll
    for (int o = 32; o > 0; o >>= 1) s += __shfl_down(s, o, 64);
    __shared__ float wsum[4];
    int lane = threadIdx.x & 63, wv = threadIdx.x >> 6;
    if (lane == 0) wsum[wv] = s;
    __syncthreads();
    if (threadIdx.x == 0) {
        float tot = wsum[0] + wsum[1] + wsum[2] + wsum[3];
        atomicAdd(slot, tot);
    }
}

// ---------------- H_out = (H/||H||_F)^2 = H*H / fslot ----------------
__global__ void sqmm_kernel(const float2* __restrict__ A, float2* __restrict__ C,
                            const float* __restrict__ fslot) {
    __shared__ float2 As[32][33];
    __shared__ float2 Bs[32][33];
    float inv = 1.0f / fslot[0];
    int tx = threadIdx.x, ty = threadIdx.y;
    int t = ty * 16 + tx;
    int r0 = blockIdx.y * 32, c0 = blockIdx.x * 32;
    float2 acc[2][2] = {};
    for (int k0 = 0; k0 < Mm; k0 += 32) {
        #pragma unroll
        for (int i = 0; i < 4; ++i) {
            int idx = t + i * 256;
            int rr = idx >> 5, cc = idx & 31;
            int gr = r0 + rr, gk = k0 + cc;
            As[rr][cc] = (gr < Mm && gk < Mm) ? A[gr * Mm + gk] : make_float2(0.f, 0.f);
            int gk2 = k0 + rr, gc = c0 + cc;
            Bs[rr][cc] = (gk2 < Mm && gc < Mm) ? A[gk2 * Mm + gc] : make_float2(0.f, 0.f);
        }
        __syncthreads();
        #pragma unroll 8
        for (int kk = 0; kk < 32; ++kk) {
            float2 a0 = As[ty * 2][kk], a1 = As[ty * 2 + 1][kk];
            float2 b0 = Bs[kk][tx * 2], b1 = Bs[kk][tx * 2 + 1];
            cmac(acc[0][0], a0, b0); cmac(acc[0][1], a0, b1);
            cmac(acc[1][0], a1, b0); cmac(acc[1][1], a1, b1);
        }
        __syncthreads();
    }
    #pragma unroll
    for (int i = 0; i < 2; ++i) {
        int gr = r0 + ty * 2 + i;
        #pragma unroll
        for (int j = 0; j < 2; ++j) {
            int gc = c0 + tx * 2 + j;
            if (gr < Mm && gc < Mm)
                C[gr * Mm + gc] = make_float2(acc[i][j].x * inv, acc[i][j].y * inv);
        }
    }
}

// ---------------- Rayleigh quotient: lambda = v^H G v / v^H v, v = H*ones ----------------
__global__ void rayleigh_kernel(const float2* __restrict__ H, const float2* __restrict__ G,
                                float* __restrict__ sc) {
    __shared__ float2 v[Mm];
    __shared__ float rn[320], rd[320];
    int t = threadIdx.x;
    if (t < Mm) {
        float2 s = make_float2(0.f, 0.f);
        for (int j = 0; j < Mm; ++j) { float2 h = H[t * Mm + j]; s.x += h.x; s.y += h.y; }
        v[t] = s;
    }
    __syncthreads();
    float num = 0.f, den = 0.f;
    if (t < Mm) {
        float2 u = make_float2(0.f, 0.f);
        for (int k = 0; k < Mm; ++k) {
            float2 g = G[k * Mm + t];   // G[t][k] = conj(G[k][t]) (Hermitian), coalesced read
            float2 vk = v[k];
            // u += conj(g) * vk
            u.x = fmaf(g.x, vk.x, u.x); u.x = fmaf(g.y, vk.y, u.x);
            u.y = fmaf(g.x, vk.y, u.y); u.y = fmaf(-g.y, vk.x, u.y);
        }
        float2 vt = v[t];
        num = vt.x * u.x + vt.y * u.y;  // Re(conj(v)*u)
        den = vt.x * vt.x + vt.y * vt.y;
    }
    rn[t] = num; rd[t] = den;
    __syncthreads();
    if (t == 0) {
        float sn = 0.f, sd = 0.f;
        for (int i = 0; i < 320; ++i) { sn += rn[i]; sd += rd[i]; }
        float lam = sn / sd;
        float step = 1.0f / lam;
        sc[0] = step;
        sc[1] = 0.1f * step;
    }
}

// ---------------- GEMM1: err[b][m] = sum_n w[b][n]*phi[m][n] - r[b][m] ----------------
// tiles 64(b) x 64(m), thread-tile 4x4, KT=16, K = Nn = 984
__global__ __launch_bounds__(256) void gemm_err_kernel(
    const float2* __restrict__ w, const float* __restrict__ pr, const float* __restrict__ pi,
    const float* __restrict__ rr, const float* __restrict__ ri, float2* __restrict__ err) {
    __shared__ float2 As[64][KT + 2];   // [b][k], row stride 144B (16B aligned, +4 bank skew)
    __shared__ float2 Bs[KT][64 + 2];   // [k][m], row stride 528B
    int t = threadIdx.x;
    int tx = t & 15, ty = t >> 4;
    int b0 = blockIdx.x * 64;
    int c0 = blockIdx.y * 64;
    float2 acc[4][4] = {};

    for (int k0 = 0; k0 < Nn; k0 += KT) {
        // stage A (w): 64 rows x 16 k = 512 float4 -> 2/thread
        #pragma unroll
        for (int rep = 0; rep < 2; ++rep) {
            int idx = t + rep * 256;
            int ra = idx >> 3, sa = idx & 7;      // float4 slot (2 complex)
            int gk = k0 + sa * 2;
            float4 v = make_float4(0.f, 0.f, 0.f, 0.f);
            if (gk < Nn) v = *reinterpret_cast<const float4*>(&w[(size_t)(b0 + ra) * Nn + gk]);
            *reinterpret_cast<float4*>(&As[ra][sa * 2]) = v;
        }
        // stage B (phi, transposed into [k][m]): per plane 64 rows(m) x 4 float4 = 256 -> 1/thread
        {
            int rb = t >> 2, sb = t & 3;
            int gm = c0 + rb, gk = k0 + sb * 4;
            float4 vr = make_float4(0.f, 0.f, 0.f, 0.f), vi = vr;
            if (gm < Mm && gk < Nn) {
                vr = *reinterpret_cast<const float4*>(&pr[(size_t)gm * Nn + gk]);
                vi = *reinterpret_cast<const float4*>(&pi[(size_t)gm * Nn + gk]);
            }
            Bs[sb * 4 + 0][rb] = make_float2(vr.x, vi.x);
            Bs[sb * 4 + 1][rb] = make_float2(vr.y, vi.y);
            Bs[sb * 4 + 2][rb] = make_float2(vr.z, vi.z);
            Bs[sb * 4 + 3][rb] = make_float2(vr.w, vi.w);
        }
        __syncthreads();
        #pragma unroll
        for (int kk = 0; kk < KT; ++kk) {
            float2 a[4], b[4];
            #pragma unroll
            for (int i = 0; i < 4; ++i) a[i] = As[ty * 4 + i][kk];
            *reinterpret_cast<float4*>(&b[0]) = *reinterpret_cast<const float4*>(&Bs[kk][tx * 4]);
            *reinterpret_cast<float4*>(&b[2]) = *reinterpret_cast<const float4*>(&Bs[kk][tx * 4 + 2]);
            #pragma unroll
            for (int i = 0; i < 4; ++i)
                #pragma unroll
                for (int j = 0; j < 4; ++j) cmac(acc[i][j], a[i], b[j]);
        }
        __syncthreads();
    }
    #pragma unroll
    for (int i = 0; i < 4; ++i) {
        int gb = b0 + ty * 4 + i;
        #pragma unroll
        for (int j = 0; j < 4; ++j) {
            int gm = c0 + tx * 4 + j;
            if (gm < Mm) {
                float2 e = acc[i][j];
                e.x -= rr[(size_t)gb * Mm + gm];
                e.y -= ri[(size_t)gb * Mm + gm];
                err[(size_t)gb * Mm + gm] = e;
            }
        }
    }
}

// ---------------- GEMM2 fused: w = shrink(w - step * err*conj(phi)); optional |w| out ----
// tiles 64(b) x 64(n), thread-tile 4x4, KT=16, K = Mm = 306
__global__ __launch_bounds__(256) void gemm_grad_kernel(
    const float2* __restrict__ err, const float* __restrict__ pr, const float* __restrict__ pi,
    float2* __restrict__ w, const float* __restrict__ sc, float* __restrict__ out, int write_out) {
    __shared__ float2 As[64][KT + 2];   // [b][k=m]
    __shared__ float2 Bs[KT][64 + 2];   // [k=m][n], conj pre-applied
    int t = threadIdx.x;
    int tx = t & 15, ty = t >> 4;
    int b0 = blockIdx.x * 64;
    int c0 = blockIdx.y * 64;
    float2 acc[4][4] = {};

    for (int k0 = 0; k0 < Mm; k0 += KT) {
        #pragma unroll
        for (int rep = 0; rep < 2; ++rep) {
            int idx = t + rep * 256;
            int ra = idx >> 3, sa = idx & 7;
            int gk = k0 + sa * 2;
            float4 v = make_float4(0.f, 0.f, 0.f, 0.f);
            if (gk < Mm) v = *reinterpret_cast<const float4*>(&err[(size_t)(b0 + ra) * Mm + gk]);
            *reinterpret_cast<float4*>(&As[ra][sa * 2]) = v;
        }
        {
            int rb = t >> 4, sb = t & 15;   // k-row rb (0..15), 4-col slot sb
            int gm = k0 + rb, gn = c0 + sb * 4;
            float4 vr = make_float4(0.f, 0.f, 0.f, 0.f), vi = vr;
            if (gm < Mm && gn < Nn) {
                vr = *reinterpret_cast<const float4*>(&pr[(size_t)gm * Nn + gn]);
                vi = *reinterpret_cast<const float4*>(&pi[(size_t)gm * Nn + gn]);
            }
            *reinterpret_cast<float4*>(&Bs[rb][sb * 4 + 0]) = make_float4(vr.x, -vi.x, vr.y, -vi.y);
            *reinterpret_cast<float4*>(&Bs[rb][sb * 4 + 2]) = make_float4(vr.z, -vi.z, vr.w, -vi.w);
        }
        __syncthreads();
        #pragma unroll
        for (int kk = 0; kk < KT; ++kk) {
            float2 a[4], b[4];
            #pragma unroll
            for (int i = 0; i < 4; ++i) a[i] = As[ty * 4 + i][kk];
            *reinterpret_cast<float4*>(&b[0]) = *reinterpret_cast<const float4*>(&Bs[kk][tx * 4]);
            *reinterpret_cast<float4*>(&b[2]) = *reinterpret_cast<const float4*>(&Bs[kk][tx * 4 + 2]);
            #pragma unroll
            for (int i = 0; i < 4; ++i)
                #pragma unroll
                for (int j = 0; j < 4; ++j) cmac(acc[i][j], a[i], b[j]);
        }
        __syncthreads();
    }
    float step = sc[0], thr = sc[1];
    #pragma unroll
    for (int i = 0; i < 4; ++i) {
        int gb = b0 + ty * 4 + i;
        #pragma unroll
        for (int j = 0; j < 4; ++j) {
            int gn = c0 + tx * 4 + j;
            if (gn < Nn) {
                size_t idx = (size_t)gb * Nn + gn;
                float2 wv = w[idx];
                float xr = fmaf(-step, acc[i][j].x, wv.x);
                float xi = fmaf(-step, acc[i][j].y, wv.y);
                float mag = sqrtf(xr * xr + xi * xi);
                float nm = mag - thr;
                float f = (nm > 0.f) ? (nm / mag) : 0.f;
                w[idx] = make_float2(xr * f, xi * f);
                if (write_out) out[idx] = (nm > 0.f) ? nm : 0.f;
            }
        }
    }
}

extern "C" void kernel_launch(void* const* d_in, const int* in_sizes, int n_in,
                              void* d_out, int out_size, void* d_ws, size_t ws_size,
                              hipStream_t stream) {
    const float* rr = (const float*)d_in[0];   // r_real  [B,M]
    const float* ri = (const float*)d_in[1];   // r_imag  [B,M]
    const float* pr = (const float*)d_in[2];   // phi_real [M,N]
    const float* pi = (const float*)d_in[3];   // phi_imag [M,N]
    float* out = (float*)d_out;                // |w| [B,N]

    // workspace carve-up (all 16B aligned)
    char* ws = (char*)d_ws;
    size_t off = 0;
    float2* w = (float2*)(ws + off);   off += (size_t)Bb * Nn * sizeof(float2);   // 32.2 MB
    float2* err = (float2*)(ws + off); off += (size_t)Bb * Mm * sizeof(float2);   // 10.0 MB
    float2* G = (float2*)(ws + off);   off += (size_t)Mm * Mm * sizeof(float2);
    float2* H1 = (float2*)(ws + off);  off += (size_t)Mm * Mm * sizeof(float2);
    float2* H2 = (float2*)(ws + off);  off += (size_t)Mm * Mm * sizeof(float2);
    float* slots = (float*)(ws + off); off += 64 * sizeof(float);                 // frob[0..15], sc at +32
    float* sc = slots + 32;

    // init (harness poisons ws before every launch)
    hipMemsetAsync(w, 0, (size_t)Bb * Nn * sizeof(float2), stream);
    hipMemsetAsync(slots, 0, 64 * sizeof(float), stream);

    // ---- spectral norm: G = phi phi^H ; 16x (normalize + square) ; Rayleigh ----
    gram_kernel<<<dim3(20, 20), dim3(16, 16), 0, stream>>>(pr, pi, G);
    float2* bufs[2] = { H1, H2 };
    const float2* src = G;
    for (int s = 0; s < KSQ; ++s) {
        frob_kernel<<<128, 256, 0, stream>>>(src, slots + s, Mm * Mm);
        float2* dst = bufs[s & 1];
        sqmm_kernel<<<dim3(10, 10), dim3(16, 16), 0, stream>>>(src, dst, slots + s);
        src = dst;
    }
    rayleigh_kernel<<<1, 320, 0, stream>>>(src, G, sc);

    // ---- ISTA main loop ----
    for (int it = 0; it < ITERS; ++it) {
        gemm_err_kernel<<<dim3(Bb / 64, (Mm + 63) / 64), 256, 0, stream>>>(w, pr, pi, rr, ri, err);
        gemm_grad_kernel<<<dim3(Bb / 64, (Nn + 63) / 64), 256, 0, stream>>>(
            err, pr, pi, w, sc, out, it == ITERS - 1 ? 1 : 0);
    }
}

// Round 3
// 5261.456 us; speedup vs baseline: 3.2562x; 3.2562x over previous
//
#include <hip/hip_runtime.h>
#include <math.h>

#define Bb 4096
#define Mm 306
#define Nn 984      // complex cols
#define NCP 1024    // padded complex cols
#define KA 2048     // w real k-cols (padded)
#define KB 4096     // B k-cols: [hi 2048 | lo 2048]
#define JR 2048     // B rows = real output cols (padded)
#define ITERS 50
#define KSQ 13      // squaring stages: G^(2^13)

typedef __bf16 bf16x8 __attribute__((ext_vector_type(8)));
typedef float f32x4 __attribute__((ext_vector_type(4)));

__device__ __forceinline__ void cmac(float2& c, const float2 a, const float2 b) {
    c.x = fmaf(a.x, b.x, c.x);
    c.x = fmaf(-a.y, b.y, c.x);
    c.y = fmaf(a.x, b.y, c.y);
    c.y = fmaf(a.y, b.x, c.y);
}

__device__ __forceinline__ unsigned short bfbits(float v) {
    __bf16 h = (__bf16)v;
    union { __bf16 b; unsigned short u; } cv; cv.b = h; return cv.u;
}

__device__ __forceinline__ void load_lds16(const void* g, void* l) {
    __builtin_amdgcn_global_load_lds((const __attribute__((address_space(1))) void*)g,
                                     (__attribute__((address_space(3))) void*)l, 16, 0, 0);
}

// ---- swizzled uint (4B) index for A operand (w bf16), logical (row b, complex col c) ----
// layout: [bblk=b>>7][kta=c>>5][kq=(c>>2)&7][m=b&127] 16B units, +intra-unit (c&3)
__device__ __forceinline__ size_t swzA(int b, int c) {
    return ((size_t)(((b >> 7) * 32 + (c >> 5)) * 1024 + ((c >> 2) & 7) * 128 + (b & 127))) * 4 + (c & 3);
}
// ---- swizzled uint index for B operand (Q bf16), logical (row jr, uint col q) ----
// layout: [nblk=jr>>7][ktb=q>>5][kq=(q>>2)&7][m=jr&127] 16B units, +intra-unit (q&3)
__device__ __forceinline__ size_t swzB(int jr, int q) {
    return ((size_t)(((jr >> 7) * 64 + (q >> 5)) * 1024 + ((q >> 2) & 7) * 128 + (jr & 127))) * 4 + (q & 3);
}

// ---------------- G = phi * phi^H  (306x306 complex) ----------------
__global__ void gram_kernel(const float* __restrict__ pr, const float* __restrict__ pi,
                            float2* __restrict__ G) {
    int j = blockIdx.x * 16 + threadIdx.x;
    int i = blockIdx.y * 16 + threadIdx.y;
    if (i >= Mm || j >= Mm) return;
    const float* pri = pr + (size_t)i * Nn;
    const float* pii = pi + (size_t)i * Nn;
    const float* prj = pr + (size_t)j * Nn;
    const float* pij = pi + (size_t)j * Nn;
    float ar = 0.f, ai = 0.f;
    for (int n = 0; n < Nn; ++n) {
        float xr = pri[n], xi = pii[n], yr = prj[n], yi = pij[n];
        ar = fmaf(xr, yr, ar); ar = fmaf(xi, yi, ar);
        ai = fmaf(xi, yr, ai); ai = fmaf(-xr, yi, ai);
    }
    G[i * Mm + j] = make_float2(ar, ai);
}

// ---------------- Frobenius^2 reduction ----------------
__global__ void frob_kernel(const float2* __restrict__ H, float* __restrict__ slot, int n) {
    int idx = blockIdx.x * blockDim.x + threadIdx.x;
    int stride = gridDim.x * blockDim.x;
    float s = 0.f;
    for (int i = idx; i < n; i += stride) {
        float2 v = H[i];
        s = fmaf(v.x, v.x, s);
        s = fmaf(v.y, v.y, s);
    }
    #pragma unroll
    for (int o = 32; o > 0; o >>= 1) s += __shfl_down(s, o, 64);
    __shared__ float wsum[4];
    int lane = threadIdx.x & 63, wv = threadIdx.x >> 6;
    if (lane == 0) wsum[wv] = s;
    __syncthreads();
    if (threadIdx.x == 0) atomicAdd(slot, wsum[0] + wsum[1] + wsum[2] + wsum[3]);
}

// ---------------- H_out = (H/||H||_F)^2 ----------------
__global__ void sqmm_kernel(const float2* __restrict__ A, float2* __restrict__ C,
                            const float* __restrict__ fslot) {
    __shared__ float2 As[32][33];
    __shared__ float2 Bs[32][33];
    float inv = 1.0f / fslot[0];
    int tx = threadIdx.x, ty = threadIdx.y;
    int t = ty * 16 + tx;
    int r0 = blockIdx.y * 32, c0 = blockIdx.x * 32;
    float2 acc[2][2] = {};
    for (int k0 = 0; k0 < Mm; k0 += 32) {
        #pragma unroll
        for (int i = 0; i < 4; ++i) {
            int idx = t + i * 256;
            int rr = idx >> 5, cc = idx & 31;
            int gr = r0 + rr, gk = k0 + cc;
            As[rr][cc] = (gr < Mm && gk < Mm) ? A[gr * Mm + gk] : make_float2(0.f, 0.f);
            int gk2 = k0 + rr, gc = c0 + cc;
            Bs[rr][cc] = (gk2 < Mm && gc < Mm) ? A[gk2 * Mm + gc] : make_float2(0.f, 0.f);
        }
        __syncthreads();
        #pragma unroll 8
        for (int kk = 0; kk < 32; ++kk) {
            float2 a0 = As[ty * 2][kk], a1 = As[ty * 2 + 1][kk];
            float2 b0 = Bs[kk][tx * 2], b1 = Bs[kk][tx * 2 + 1];
            cmac(acc[0][0], a0, b0); cmac(acc[0][1], a0, b1);
            cmac(acc[1][0], a1, b0); cmac(acc[1][1], a1, b1);
        }
        __syncthreads();
    }
    #pragma unroll
    for (int i = 0; i < 2; ++i) {
        int gr = r0 + ty * 2 + i;
        #pragma unroll
        for (int j = 0; j < 2; ++j) {
            int gc = c0 + tx * 2 + j;
            if (gr < Mm && gc < Mm)
                C[gr * Mm + gc] = make_float2(acc[i][j].x * inv, acc[i][j].y * inv);
        }
    }
}

// ---------------- Rayleigh: lambda = v^H G v / v^H v, v = H*ones ----------------
__global__ void rayleigh_kernel(const float2* __restrict__ H, const float2* __restrict__ G,
                                float* __restrict__ sc) {
    __shared__ float2 v[Mm];
    __shared__ float rn[320], rd[320];
    int t = threadIdx.x;
    if (t < Mm) {
        float2 s = make_float2(0.f, 0.f);
        for (int j = 0; j < Mm; ++j) { float2 h = H[t * Mm + j]; s.x += h.x; s.y += h.y; }
        v[t] = s;
    }
    __syncthreads();
    float num = 0.f, den = 0.f;
    if (t < Mm) {
        float2 u = make_float2(0.f, 0.f);
        for (int k = 0; k < Mm; ++k) {
            float2 g = G[k * Mm + t];
            float2 vk = v[k];
            u.x = fmaf(g.x, vk.x, u.x); u.x = fmaf(g.y, vk.y, u.x);
            u.y = fmaf(g.x, vk.y, u.y); u.y = fmaf(-g.y, vk.x, u.y);
        }
        float2 vt = v[t];
        num = vt.x * u.x + vt.y * u.y;
        den = vt.x * vt.x + vt.y * vt.y;
    }
    rn[t] = num; rd[t] = den;
    __syncthreads();
    if (t == 0) {
        float sn = 0.f, sd = 0.f;
        for (int i = 0; i < 320; ++i) { sn += rn[i]; sd += rd[i]; }
        float lam = sn / sd;
        float step = 1.0f / lam;
        sc[0] = step;
        sc[1] = 0.1f * step;
    }
}

// ---------------- qpack: Q[n][c] = sum_m phi[m][n]*conj(phi[m][c]) -> swizzled bf16 hi/lo
// B row jr = (c>>4)*32 + (c&15) [Re], +16 [Im]; uint col q = n (hi), 1024+n (lo)
__global__ void qpack_kernel(const float* __restrict__ pr, const float* __restrict__ pi,
                             unsigned int* __restrict__ Bu) {
    __shared__ float2 Pn[16][33];
    __shared__ float2 Pc[16][33];
    int t = threadIdx.x;
    int tx = t & 15, ty = t >> 4;
    int n0 = blockIdx.x * 32, c0 = blockIdx.y * 32;
    float2 q[2][2] = {};
    for (int m0 = 0; m0 < Mm; m0 += 16) {
        #pragma unroll
        for (int rep = 0; rep < 2; ++rep) {
            int idx = t + rep * 256;
            int mm = idx >> 5, col = idx & 31;
            int gm = m0 + mm;
            float2 a = make_float2(0.f, 0.f), b = make_float2(0.f, 0.f);
            if (gm < Mm) {
                if (n0 + col < Nn) a = make_float2(pr[(size_t)gm * Nn + n0 + col], pi[(size_t)gm * Nn + n0 + col]);
                if (c0 + col < Nn) b = make_float2(pr[(size_t)gm * Nn + c0 + col], pi[(size_t)gm * Nn + c0 + col]);
            }
            Pn[mm][col] = a; Pc[mm][col] = b;
        }
        __syncthreads();
        #pragma unroll
        for (int mm = 0; mm < 16; ++mm) {
            float2 a0 = Pn[mm][ty * 2], a1 = Pn[mm][ty * 2 + 1];
            float2 b0 = Pc[mm][tx * 2], b1 = Pc[mm][tx * 2 + 1];
            // q += a * conj(b)
            #define QMAC(qq, aa, bb) \
                qq.x = fmaf(aa.x, bb.x, qq.x); qq.x = fmaf(aa.y, bb.y, qq.x); \
                qq.y = fmaf(aa.y, bb.x, qq.y); qq.y = fmaf(-aa.x, bb.y, qq.y);
            QMAC(q[0][0], a0, b0) QMAC(q[0][1], a0, b1)
            QMAC(q[1][0], a1, b0) QMAC(q[1][1], a1, b1)
            #undef QMAC
        }
        __syncthreads();
    }
    #pragma unroll
    for (int i = 0; i < 2; ++i) {
        int n = n0 + ty * 2 + i;
        #pragma unroll
        for (int j = 0; j < 2; ++j) {
            int c = c0 + tx * 2 + j;
            if (n < Nn && c < Nn) {
                float QR = q[i][j].x, QI = q[i][j].y;
                unsigned short hR = bfbits(QR);
                float hRf; { __bf16 h = (__bf16)QR; hRf = (float)h; }
                unsigned short lR = bfbits(QR - hRf);
                unsigned short hI = bfbits(QI);
                float hIf; { __bf16 h = (__bf16)QI; hIf = (float)h; }
                unsigned short lI = bfbits(QI - hIf);
                unsigned short nhI = hI ^ 0x8000u, nlI = lI ^ 0x8000u;
                int jr = ((c >> 4) * 32) + (c & 15);
                // hi half: uint col q = n;  lo half: q = 1024 + n
                Bu[swzB(jr, n)]             = (unsigned)hR | ((unsigned)nhI << 16);
                Bu[swzB(jr + 16, n)]        = (unsigned)hI | ((unsigned)hR << 16);
                Bu[swzB(jr, 1024 + n)]      = (unsigned)lR | ((unsigned)nlI << 16);
                Bu[swzB(jr + 16, 1024 + n)] = (unsigned)lI | ((unsigned)lR << 16);
            }
        }
    }
}

// ---------------- rphi[b][c] = sum_m r[b][m]*conj(phi[m][c]), fp32, padded [4096][1024] ---
__global__ __launch_bounds__(256) void rphi_kernel(
    const float* __restrict__ rr, const float* __restrict__ ri,
    const float* __restrict__ pr, const float* __restrict__ pi,
    float2* __restrict__ rphi) {
    __shared__ float2 As[64][18];
    __shared__ float2 Bs[16][66];
    int t = threadIdx.x;
    int tx = t & 15, ty = t >> 4;
    int b0 = blockIdx.x * 64, c0 = blockIdx.y * 64;
    float2 acc[4][4] = {};
    for (int k0 = 0; k0 < Mm; k0 += 16) {
        #pragma unroll
        for (int rep = 0; rep < 4; ++rep) {
            int idx = t + rep * 256;
            int row = idx >> 4, kk = idx & 15;
            int gk = k0 + kk;
            float re = 0.f, im = 0.f;
            if (gk < Mm) {
                re = rr[(size_t)(b0 + row) * Mm + gk];
                im = ri[(size_t)(b0 + row) * Mm + gk];
            }
            As[row][kk] = make_float2(re, im);
        }
        {
            int rb = t >> 4, sb = t & 15;
            int gm = k0 + rb, gc = c0 + sb * 4;
            float4 vr = make_float4(0.f, 0.f, 0.f, 0.f), vi = vr;
            if (gm < Mm && gc < Nn) {
                vr = *reinterpret_cast<const float4*>(&pr[(size_t)gm * Nn + gc]);
                vi = *reinterpret_cast<const float4*>(&pi[(size_t)gm * Nn + gc]);
            }
            Bs[rb][sb * 4 + 0] = make_float2(vr.x, -vi.x);
            Bs[rb][sb * 4 + 1] = make_float2(vr.y, -vi.y);
            Bs[rb][sb * 4 + 2] = make_float2(vr.z, -vi.z);
            Bs[rb][sb * 4 + 3] = make_float2(vr.w, -vi.w);
        }
        __syncthreads();
        #pragma unroll
        for (int kk = 0; kk < 16; ++kk) {
            float2 a[4], b[4];
            #pragma unroll
            for (int i = 0; i < 4; ++i) a[i] = As[ty * 4 + i][kk];
            #pragma unroll
            for (int j = 0; j < 4; ++j) b[j] = Bs[kk][tx * 4 + j];
            #pragma unroll
            for (int i = 0; i < 4; ++i)
                #pragma unroll
                for (int j = 0; j < 4; ++j) cmac(acc[i][j], a[i], b[j]);
        }
        __syncthreads();
    }
    #pragma unroll
    for (int i = 0; i < 4; ++i) {
        int gb = b0 + ty * 4 + i;
        #pragma unroll
        for (int j = 0; j < 4; ++j) {
            int gc = c0 + tx * 4 + j;
            rphi[(size_t)gb * NCP + gc] = acc[i][j];
        }
    }
}

// ---------------- main ISTA iteration: one bf16 MFMA GEMM + fused shrink epilogue -------
// acc[b][jr] = sum_k A[b][k] * B[jr][k]; A,B pre-swizzled [tile][kq][m] 16B-unit order
__global__ __launch_bounds__(256, 2) void ista3_kernel(
    const __bf16* __restrict__ wbi, const __bf16* __restrict__ Bp,
    unsigned int* __restrict__ wbo,
    float2* __restrict__ w32, const float2* __restrict__ rphi,
    const float* __restrict__ sc, float* __restrict__ out, int last) {
    __shared__ __bf16 As[8192];   // [kq 0..7][m 0..127] 16B units
    __shared__ __bf16 Bs[8192];
    int tid = threadIdx.x;
    int lane = tid & 63, wv = tid >> 6;
    int wm = wv & 1, wn = wv >> 1;
    int bblk = blockIdx.x, nblk = blockIdx.y;
    int b0 = bblk * 128;
    int n0 = nblk * 128;          // jr (real-col) base
    int tcol = lane & 15, quad = lane >> 4;

    f32x4 acc[4][4] = {};

    int colA = wm * 64 + tcol;
    int colB = wn * 64 + tcol;

    for (int kt = 0; kt < 64; ++kt) {
        int kta = kt & 31;        // A (w) reused for hi and lo halves
        #pragma unroll
        for (int c = 0; c < 4; ++c) {
            int u = c * 256 + tid;
            const char* ga = (const char*)wbi + (((size_t)(bblk * 32 + kta)) * 1024 + u) * 16;
            load_lds16(ga, &As[(size_t)(c * 256 + wv * 64) * 8]);
            const char* gb = (const char*)Bp + (((size_t)(nblk * 64 + kt)) * 1024 + u) * 16;
            load_lds16(gb, &Bs[(size_t)(c * 256 + wv * 64) * 8]);
        }
        __syncthreads();
        #pragma unroll
        for (int ks = 0; ks < 2; ++ks) {
            bf16x8 af[4], bfr[4];
            #pragma unroll
            for (int i = 0; i < 4; ++i) {
                int ua = (ks * 4 + quad) * 128 + colA + i * 16;
                af[i] = *reinterpret_cast<const bf16x8*>(&As[(size_t)ua * 8]);
                int ub = (ks * 4 + quad) * 128 + colB + i * 16;
                bfr[i] = *reinterpret_cast<const bf16x8*>(&Bs[(size_t)ub * 8]);
            }
            #pragma unroll
            for (int i = 0; i < 4; ++i)
                #pragma unroll
                for (int j = 0; j < 4; ++j)
                    acc[i][j] = __builtin_amdgcn_mfma_f32_16x16x32_bf16(af[i], bfr[j], acc[i][j], 0, 0, 0);
        }
        __syncthreads();
    }

    float step = sc[0], thr = sc[1];
    #pragma unroll
    for (int i = 0; i < 4; ++i) {
        int rbase = b0 + wm * 64 + i * 16 + quad * 4;
        #pragma unroll
        for (int p = 0; p < 2; ++p) {
            int c = (n0 >> 1) + wn * 32 + p * 16 + tcol;   // complex col
            #pragma unroll
            for (int r = 0; r < 4; ++r) {
                int row = rbase + r;
                size_t idx = (size_t)row * NCP + c;
                float2 wvv = w32[idx];
                float2 rp = rphi[idx];
                float gr = acc[i][2 * p][r] - rp.x;
                float gi = acc[i][2 * p + 1][r] - rp.y;
                float zr = fmaf(-step, gr, wvv.x);
                float zi = fmaf(-step, gi, wvv.y);
                float mag = sqrtf(zr * zr + zi * zi);
                float nm = mag - thr;
                float f = (nm > 0.f) ? (nm / mag) : 0.f;
                float orr = zr * f, oii = zi * f;
                w32[idx] = make_float2(orr, oii);
                wbo[swzA(row, c)] = (unsigned)bfbits(orr) | ((unsigned)bfbits(oii) << 16);
                if (last && c < Nn) out[(size_t)row * Nn + c] = fmaxf(nm, 0.f);
            }
        }
    }
}

extern "C" void kernel_launch(void* const* d_in, const int* in_sizes, int n_in,
                              void* d_out, int out_size, void* d_ws, size_t ws_size,
                              hipStream_t stream) {
    const float* rr = (const float*)d_in[0];
    const float* ri = (const float*)d_in[1];
    const float* pr = (const float*)d_in[2];
    const float* pi = (const float*)d_in[3];
    float* out = (float*)d_out;

    char* ws = (char*)d_ws;
    size_t off = 0;
    float2* w32 = (float2*)(ws + off);  off += (size_t)Bb * NCP * sizeof(float2);   // 32 MB
    __bf16* wb0 = (__bf16*)(ws + off);  off += (size_t)Bb * KA * sizeof(__bf16);    // 16 MB
    __bf16* wb1 = (__bf16*)(ws + off);  off += (size_t)Bb * KA * sizeof(__bf16);    // 16 MB
    __bf16* Bp  = (__bf16*)(ws + off);  off += (size_t)JR * KB * sizeof(__bf16);    // 16 MB
    float2* rphi = (float2*)(ws + off); off += (size_t)Bb * NCP * sizeof(float2);   // 32 MB
    float2* G = (float2*)(ws + off);    off += (size_t)Mm * Mm * sizeof(float2);
    float2* H1 = (float2*)(ws + off);   off += (size_t)Mm * Mm * sizeof(float2);
    float2* H2 = (float2*)(ws + off);   off += (size_t)Mm * Mm * sizeof(float2);
    float* slots = (float*)(ws + off);  off += 64 * sizeof(float);
    float* sc = slots + 32;

    (void)hipMemsetAsync(w32, 0, (size_t)Bb * NCP * sizeof(float2), stream);
    (void)hipMemsetAsync(wb0, 0, (size_t)Bb * KA * sizeof(__bf16), stream);
    (void)hipMemsetAsync(wb1, 0, (size_t)Bb * KA * sizeof(__bf16), stream);
    (void)hipMemsetAsync(Bp, 0, (size_t)JR * KB * sizeof(__bf16), stream);
    (void)hipMemsetAsync(slots, 0, 64 * sizeof(float), stream);

    // spectral norm chain on G (306x306)
    gram_kernel<<<dim3(20, 20), dim3(16, 16), 0, stream>>>(pr, pi, G);
    float2* bufs[2] = { H1, H2 };
    const float2* src = G;
    for (int s = 0; s < KSQ; ++s) {
        frob_kernel<<<128, 256, 0, stream>>>(src, slots + s, Mm * Mm);
        float2* dst = bufs[s & 1];
        sqmm_kernel<<<dim3(10, 10), dim3(16, 16), 0, stream>>>(src, dst, slots + s);
        src = dst;
    }
    rayleigh_kernel<<<1, 320, 0, stream>>>(src, G, sc);

    // precompute packed operator and rphi
    qpack_kernel<<<dim3(31, 31), 256, 0, stream>>>(pr, pi, (unsigned int*)Bp);
    rphi_kernel<<<dim3(64, 16), 256, 0, stream>>>(rr, ri, pr, pi, rphi);

    // ISTA main loop: one fused MFMA GEMM per iteration, w_bf16 ping-pong
    __bf16* wbuf[2] = { wb0, wb1 };
    for (int it = 0; it < ITERS; ++it) {
        ista3_kernel<<<dim3(32, 16), 256, 0, stream>>>(
            wbuf[it & 1], Bp, (unsigned int*)wbuf[(it + 1) & 1], w32, rphi, sc, out,
            it == ITERS - 1 ? 1 : 0);
    }
}

// Round 4
// 4721.169 us; speedup vs baseline: 3.6289x; 1.1144x over previous
//
#include <hip/hip_runtime.h>
#include <math.h>

#define Bb 4096
#define Mm 306
#define Nn 984      // complex cols
#define NCP 1024    // padded complex cols
#define KA 2048     // w real k-cols (padded)
#define KB 4096     // B k-cols: [hi 2048 | lo 2048]
#define JR 2048     // B rows = real output cols (padded)
#define ITERS 50
#define KSQ 13      // squaring stages: G^(2^13)

typedef __bf16 bf16x8 __attribute__((ext_vector_type(8)));
typedef float f32x4 __attribute__((ext_vector_type(4)));
typedef float f32x16 __attribute__((ext_vector_type(16)));

__device__ __forceinline__ void cmac(float2& c, const float2 a, const float2 b) {
    c.x = fmaf(a.x, b.x, c.x);
    c.x = fmaf(-a.y, b.y, c.x);
    c.y = fmaf(a.x, b.y, c.y);
    c.y = fmaf(a.y, b.x, c.y);
}

__device__ __forceinline__ unsigned short bfbits(float v) {
    __bf16 h = (__bf16)v;
    union { __bf16 b; unsigned short u; } cv; cv.b = h; return cv.u;
}

__device__ __forceinline__ void load_lds16(const void* g, void* l) {
    __builtin_amdgcn_global_load_lds((const __attribute__((address_space(1))) void*)g,
                                     (__attribute__((address_space(3))) void*)l, 16, 0, 0);
}

// ---- swizzled uint (4B) index for A operand (w bf16), logical (row b, complex col c) ----
// layout: [bblk=b>>7][kta=c>>5][kq=(c>>2)&7][m=b&127] 16B units, +intra-unit (c&3)
__device__ __forceinline__ size_t swzA(int b, int c) {
    return ((size_t)(((b >> 7) * 32 + (c >> 5)) * 1024 + ((c >> 2) & 7) * 128 + (b & 127))) * 4 + (c & 3);
}
// ---- swizzled uint index for B operand (Q bf16), logical (row jr, uint col q) ----
__device__ __forceinline__ size_t swzB(int jr, int q) {
    return ((size_t)(((jr >> 7) * 64 + (q >> 5)) * 1024 + ((q >> 2) & 7) * 128 + (jr & 127))) * 4 + (q & 3);
}

// ---------------- G = phi * phi^H  (306x306 complex) ----------------
__global__ void gram_kernel(const float* __restrict__ pr, const float* __restrict__ pi,
                            float2* __restrict__ G) {
    int j = blockIdx.x * 16 + threadIdx.x;
    int i = blockIdx.y * 16 + threadIdx.y;
    if (i >= Mm || j >= Mm) return;
    const float* pri = pr + (size_t)i * Nn;
    const float* pii = pi + (size_t)i * Nn;
    const float* prj = pr + (size_t)j * Nn;
    const float* pij = pi + (size_t)j * Nn;
    float ar = 0.f, ai = 0.f;
    for (int n = 0; n < Nn; ++n) {
        float xr = pri[n], xi = pii[n], yr = prj[n], yi = pij[n];
        ar = fmaf(xr, yr, ar); ar = fmaf(xi, yi, ar);
        ai = fmaf(xi, yr, ai); ai = fmaf(-xr, yi, ai);
    }
    G[i * Mm + j] = make_float2(ar, ai);
}

// ---------------- Frobenius^2 reduction ----------------
__global__ void frob_kernel(const float2* __restrict__ H, float* __restrict__ slot, int n) {
    int idx = blockIdx.x * blockDim.x + threadIdx.x;
    int stride = gridDim.x * blockDim.x;
    float s = 0.f;
    for (int i = idx; i < n; i += stride) {
        float2 v = H[i];
        s = fmaf(v.x, v.x, s);
        s = fmaf(v.y, v.y, s);
    }
    #pragma unroll
    for (int o = 32; o > 0; o >>= 1) s += __shfl_down(s, o, 64);
    __shared__ float wsum[4];
    int lane = threadIdx.x & 63, wv = threadIdx.x >> 6;
    if (lane == 0) wsum[wv] = s;
    __syncthreads();
    if (threadIdx.x == 0) atomicAdd(slot, wsum[0] + wsum[1] + wsum[2] + wsum[3]);
}

// ---------------- C += (A/||A||_F)^2 partial (split-K, C pre-zeroed) ----------------
__global__ void sqmm_kernel(const float2* __restrict__ A, float2* __restrict__ C,
                            const float* __restrict__ fslot) {
    __shared__ float2 As[32][33];
    __shared__ float2 Bs[32][33];
    float inv = 1.0f / fslot[0];
    int tx = threadIdx.x, ty = threadIdx.y;
    int t = ty * 16 + tx;
    int r0 = blockIdx.y * 32, c0 = blockIdx.x * 32;
    int zs = blockIdx.z * 80;
    int ze = zs + 80 < Mm ? zs + 80 : Mm;
    float2 acc[2][2] = {};
    for (int k0 = zs; k0 < ze; k0 += 32) {
        #pragma unroll
        for (int i = 0; i < 4; ++i) {
            int idx = t + i * 256;
            int rr = idx >> 5, cc = idx & 31;
            int gr = r0 + rr, gk = k0 + cc;
            As[rr][cc] = (gr < Mm && gk < ze) ? A[gr * Mm + gk] : make_float2(0.f, 0.f);
            int gk2 = k0 + rr, gc = c0 + cc;
            Bs[rr][cc] = (gk2 < ze && gc < Mm) ? A[gk2 * Mm + gc] : make_float2(0.f, 0.f);
        }
        __syncthreads();
        #pragma unroll 8
        for (int kk = 0; kk < 32; ++kk) {
            float2 a0 = As[ty * 2][kk], a1 = As[ty * 2 + 1][kk];
            float2 b0 = Bs[kk][tx * 2], b1 = Bs[kk][tx * 2 + 1];
            cmac(acc[0][0], a0, b0); cmac(acc[0][1], a0, b1);
            cmac(acc[1][0], a1, b0); cmac(acc[1][1], a1, b1);
        }
        __syncthreads();
    }
    #pragma unroll
    for (int i = 0; i < 2; ++i) {
        int gr = r0 + ty * 2 + i;
        #pragma unroll
        for (int j = 0; j < 2; ++j) {
            int gc = c0 + tx * 2 + j;
            if (gr < Mm && gc < Mm) {
                atomicAdd(&C[gr * Mm + gc].x, acc[i][j].x * inv);
                atomicAdd(&C[gr * Mm + gc].y, acc[i][j].y * inv);
            }
        }
    }
}

// ---------------- Rayleigh: lambda = v^H G v / v^H v, v = H*ones ----------------
__global__ void rayleigh_kernel(const float2* __restrict__ H, const float2* __restrict__ G,
                                float* __restrict__ sc) {
    __shared__ float2 v[Mm];
    __shared__ float rn[320], rd[320];
    int t = threadIdx.x;
    if (t < Mm) {
        float2 s = make_float2(0.f, 0.f);
        for (int j = 0; j < Mm; ++j) { float2 h = H[t * Mm + j]; s.x += h.x; s.y += h.y; }
        v[t] = s;
    }
    __syncthreads();
    float num = 0.f, den = 0.f;
    if (t < Mm) {
        float2 u = make_float2(0.f, 0.f);
        for (int k = 0; k < Mm; ++k) {
            float2 g = G[k * Mm + t];
            float2 vk = v[k];
            u.x = fmaf(g.x, vk.x, u.x); u.x = fmaf(g.y, vk.y, u.x);
            u.y = fmaf(g.x, vk.y, u.y); u.y = fmaf(-g.y, vk.x, u.y);
        }
        float2 vt = v[t];
        num = vt.x * u.x + vt.y * u.y;
        den = vt.x * vt.x + vt.y * vt.y;
    }
    rn[t] = num; rd[t] = den;
    __syncthreads();
    if (t == 0) {
        float sn = 0.f, sd = 0.f;
        for (int i = 0; i < 320; ++i) { sn += rn[i]; sd += rd[i]; }
        float lam = sn / sd;
        float step = 1.0f / lam;
        sc[0] = step;
        sc[1] = 0.1f * step;
    }
}

// ---------------- qpack: M = -step*Q (Q[n][c] = sum_m phi[m][n]*conj(phi[m][c]))
// -> swizzled bf16 hi/lo. Row jr = (c>>5)*64 + (c&31) [Re], +32 [Im]; q = n (hi), 1024+n (lo)
__global__ void qpack_kernel(const float* __restrict__ pr, const float* __restrict__ pi,
                             unsigned int* __restrict__ Bu, const float* __restrict__ sc) {
    __shared__ float2 Pn[16][33];
    __shared__ float2 Pc[16][33];
    float nstep = -sc[0];
    int t = threadIdx.x;
    int tx = t & 15, ty = t >> 4;
    int n0 = blockIdx.x * 32, c0 = blockIdx.y * 32;
    float2 q[2][2] = {};
    for (int m0 = 0; m0 < Mm; m0 += 16) {
        #pragma unroll
        for (int rep = 0; rep < 2; ++rep) {
            int idx = t + rep * 256;
            int mm = idx >> 5, col = idx & 31;
            int gm = m0 + mm;
            float2 a = make_float2(0.f, 0.f), b = make_float2(0.f, 0.f);
            if (gm < Mm) {
                if (n0 + col < Nn) a = make_float2(pr[(size_t)gm * Nn + n0 + col], pi[(size_t)gm * Nn + n0 + col]);
                if (c0 + col < Nn) b = make_float2(pr[(size_t)gm * Nn + c0 + col], pi[(size_t)gm * Nn + c0 + col]);
            }
            Pn[mm][col] = a; Pc[mm][col] = b;
        }
        __syncthreads();
        #pragma unroll
        for (int mm = 0; mm < 16; ++mm) {
            float2 a0 = Pn[mm][ty * 2], a1 = Pn[mm][ty * 2 + 1];
            float2 b0 = Pc[mm][tx * 2], b1 = Pc[mm][tx * 2 + 1];
            // q += a * conj(b)
            #define QMAC(qq, aa, bb) \
                qq.x = fmaf(aa.x, bb.x, qq.x); qq.x = fmaf(aa.y, bb.y, qq.x); \
                qq.y = fmaf(aa.y, bb.x, qq.y); qq.y = fmaf(-aa.x, bb.y, qq.y);
            QMAC(q[0][0], a0, b0) QMAC(q[0][1], a0, b1)
            QMAC(q[1][0], a1, b0) QMAC(q[1][1], a1, b1)
            #undef QMAC
        }
        __syncthreads();
    }
    #pragma unroll
    for (int i = 0; i < 2; ++i) {
        int n = n0 + ty * 2 + i;
        #pragma unroll
        for (int j = 0; j < 2; ++j) {
            int c = c0 + tx * 2 + j;
            if (n < Nn && c < Nn) {
                float MR = nstep * q[i][j].x, MI = nstep * q[i][j].y;
                float MRhf; { __bf16 h = (__bf16)MR; MRhf = (float)h; }
                float MIhf; { __bf16 h = (__bf16)MI; MIhf = (float)h; }
                unsigned short hR = bfbits(MR), lR = bfbits(MR - MRhf);
                unsigned short hI = bfbits(MI), lI = bfbits(MI - MIhf);
                unsigned short nhI = hI ^ 0x8000u, nlI = lI ^ 0x8000u;
                int jr = ((c >> 5) * 64) + (c & 31);
                Bu[swzB(jr, n)]             = (unsigned)hR | ((unsigned)nhI << 16);
                Bu[swzB(jr + 32, n)]        = (unsigned)hI | ((unsigned)hR << 16);
                Bu[swzB(jr, 1024 + n)]      = (unsigned)lR | ((unsigned)nlI << 16);
                Bu[swzB(jr + 32, 1024 + n)] = (unsigned)lI | ((unsigned)lR << 16);
            }
        }
    }
}

// ---------------- rphis[b][c] = step * sum_m r[b][m]*conj(phi[m][c]), fp32 [4096][1024] ---
__global__ __launch_bounds__(256) void rphi_kernel(
    const float* __restrict__ rr, const float* __restrict__ ri,
    const float* __restrict__ pr, const float* __restrict__ pi,
    float2* __restrict__ rphis, const float* __restrict__ sc) {
    __shared__ float2 As[64][18];
    __shared__ float2 Bs[16][66];
    float step = sc[0];
    int t = threadIdx.x;
    int tx = t & 15, ty = t >> 4;
    int b0 = blockIdx.x * 64, c0 = blockIdx.y * 64;
    float2 acc[4][4] = {};
    for (int k0 = 0; k0 < Mm; k0 += 16) {
        #pragma unroll
        for (int rep = 0; rep < 4; ++rep) {
            int idx = t + rep * 256;
            int row = idx >> 4, kk = idx & 15;
            int gk = k0 + kk;
            float re = 0.f, im = 0.f;
            if (gk < Mm) {
                re = rr[(size_t)(b0 + row) * Mm + gk];
                im = ri[(size_t)(b0 + row) * Mm + gk];
            }
            As[row][kk] = make_float2(re, im);
        }
        {
            int rb = t >> 4, sb = t & 15;
            int gm = k0 + rb, gc = c0 + sb * 4;
            float4 vr = make_float4(0.f, 0.f, 0.f, 0.f), vi = vr;
            if (gm < Mm && gc < Nn) {
                vr = *reinterpret_cast<const float4*>(&pr[(size_t)gm * Nn + gc]);
                vi = *reinterpret_cast<const float4*>(&pi[(size_t)gm * Nn + gc]);
            }
            Bs[rb][sb * 4 + 0] = make_float2(vr.x, -vi.x);
            Bs[rb][sb * 4 + 1] = make_float2(vr.y, -vi.y);
            Bs[rb][sb * 4 + 2] = make_float2(vr.z, -vi.z);
            Bs[rb][sb * 4 + 3] = make_float2(vr.w, -vi.w);
        }
        __syncthreads();
        #pragma unroll
        for (int kk = 0; kk < 16; ++kk) {
            float2 a[4], b[4];
            #pragma unroll
            for (int i = 0; i < 4; ++i) a[i] = As[ty * 4 + i][kk];
            #pragma unroll
            for (int j = 0; j < 4; ++j) b[j] = Bs[kk][tx * 4 + j];
            #pragma unroll
            for (int i = 0; i < 4; ++i)
                #pragma unroll
                for (int j = 0; j < 4; ++j) cmac(acc[i][j], a[i], b[j]);
        }
        __syncthreads();
    }
    #pragma unroll
    for (int i = 0; i < 4; ++i) {
        int gb = b0 + ty * 4 + i;
        #pragma unroll
        for (int j = 0; j < 4; ++j) {
            int gc = c0 + tx * 4 + j;
            rphis[(size_t)gb * NCP + gc] = make_float2(step * acc[i][j].x, step * acc[i][j].y);
        }
    }
}

// ---------------- main ISTA iteration: 32x32x16 MFMA, A-reuse 3-buffer K-loop ----------
// acc[b][jr] = sum_k A[b][k] * M[jr][k];  z = w32 + acc + rphis; shrink; store
__global__ __launch_bounds__(256, 2) void ista4_kernel(
    const __bf16* __restrict__ wbi, const __bf16* __restrict__ Bp,
    unsigned int* __restrict__ wbo,
    float2* __restrict__ w32, const float2* __restrict__ rphis,
    const float* __restrict__ sc, float* __restrict__ out, int last) {
    __shared__ __bf16 As[8192];   // w tile: [kq 0..7][m 0..127] 16B units
    __shared__ __bf16 Bh[8192];   // M hi tile
    __shared__ __bf16 Bl[8192];   // M lo tile
    int tid = threadIdx.x;
    int lane = tid & 63, wv = tid >> 6;
    int wm = wv & 1, wn = wv >> 1;
    int bblk = blockIdx.x, nblk = blockIdx.y;
    int l31 = lane & 31, lh = lane >> 5;

    f32x16 acc[2][2] = {};   // [mt][nt: 0=Re,1=Im]

    for (int kt = 0; kt < 32; ++kt) {
        #pragma unroll
        for (int c = 0; c < 4; ++c) {
            int u = c * 256 + tid;
            const char* ga = (const char*)wbi + (((size_t)(bblk * 32 + kt)) * 1024 + u) * 16;
            load_lds16(ga, &As[(size_t)(c * 256 + wv * 64) * 8]);
            const char* gh = (const char*)Bp + (((size_t)(nblk * 64 + kt)) * 1024 + u) * 16;
            load_lds16(gh, &Bh[(size_t)(c * 256 + wv * 64) * 8]);
            const char* gl = (const char*)Bp + (((size_t)(nblk * 64 + 32 + kt)) * 1024 + u) * 16;
            load_lds16(gl, &Bl[(size_t)(c * 256 + wv * 64) * 8]);
        }
        __syncthreads();
        #pragma unroll
        for (int ks = 0; ks < 4; ++ks) {
            int kq = ks * 2 + lh;
            bf16x8 af[2], bhf[2], blf[2];
            #pragma unroll
            for (int mt = 0; mt < 2; ++mt)
                af[mt] = *reinterpret_cast<const bf16x8*>(
                    &As[(size_t)(kq * 128 + wm * 64 + mt * 32 + l31) * 8]);
            #pragma unroll
            for (int nt = 0; nt < 2; ++nt) {
                int ub = kq * 128 + wn * 64 + nt * 32 + l31;
                bhf[nt] = *reinterpret_cast<const bf16x8*>(&Bh[(size_t)ub * 8]);
                blf[nt] = *reinterpret_cast<const bf16x8*>(&Bl[(size_t)ub * 8]);
            }
            #pragma unroll
            for (int mt = 0; mt < 2; ++mt)
                #pragma unroll
                for (int nt = 0; nt < 2; ++nt) {
                    acc[mt][nt] = __builtin_amdgcn_mfma_f32_32x32x16_bf16(af[mt], bhf[nt], acc[mt][nt], 0, 0, 0);
                    acc[mt][nt] = __builtin_amdgcn_mfma_f32_32x32x16_bf16(af[mt], blf[nt], acc[mt][nt], 0, 0, 0);
                }
        }
        __syncthreads();
    }

    float thr = sc[1];
    int b0 = bblk * 128;
    int c0 = nblk * 64 + wn * 32;      // complex col base for this wave
    int c = c0 + l31;
    #pragma unroll
    for (int mt = 0; mt < 2; ++mt) {
        #pragma unroll
        for (int reg = 0; reg < 16; ++reg) {
            int row = b0 + wm * 64 + mt * 32 + ((reg & 3) + 8 * (reg >> 2) + 4 * lh);
            size_t idx = (size_t)row * NCP + c;
            float2 wvv = w32[idx];
            float2 rp = rphis[idx];
            float zr = wvv.x + acc[mt][0][reg] + rp.x;
            float zi = wvv.y + acc[mt][1][reg] + rp.y;
            float mag = sqrtf(zr * zr + zi * zi);
            float nm = mag - thr;
            float f = (nm > 0.f) ? (nm / mag) : 0.f;
            float orr = zr * f, oii = zi * f;
            w32[idx] = make_float2(orr, oii);
            wbo[swzA(row, c)] = (unsigned)bfbits(orr) | ((unsigned)bfbits(oii) << 16);
            if (last && c < Nn) out[(size_t)row * Nn + c] = fmaxf(nm, 0.f);
        }
    }
}

extern "C" void kernel_launch(void* const* d_in, const int* in_sizes, int n_in,
                              void* d_out, int out_size, void* d_ws, size_t ws_size,
                              hipStream_t stream) {
    const float* rr = (const float*)d_in[0];
    const float* ri = (const float*)d_in[1];
    const float* pr = (const float*)d_in[2];
    const float* pi = (const float*)d_in[3];
    float* out = (float*)d_out;

    char* ws = (char*)d_ws;
    size_t off = 0;
    float2* w32 = (float2*)(ws + off);  off += (size_t)Bb * NCP * sizeof(float2);   // 32 MB
    __bf16* wb0 = (__bf16*)(ws + off);  off += (size_t)Bb * KA * sizeof(__bf16);    // 16 MB
    __bf16* wb1 = (__bf16*)(ws + off);  off += (size_t)Bb * KA * sizeof(__bf16);    // 16 MB
    __bf16* Bp  = (__bf16*)(ws + off);  off += (size_t)JR * KB * sizeof(__bf16);    // 16 MB
    float2* rphis = (float2*)(ws + off); off += (size_t)Bb * NCP * sizeof(float2);  // 32 MB
    float2* G = (float2*)(ws + off);    off += (size_t)Mm * Mm * sizeof(float2);
    float2* H1 = (float2*)(ws + off);   off += (size_t)Mm * Mm * sizeof(float2);
    float2* H2 = (float2*)(ws + off);   off += (size_t)Mm * Mm * sizeof(float2);
    float* slots = (float*)(ws + off);  off += 64 * sizeof(float);
    float* sc = slots + 32;

    (void)hipMemsetAsync(w32, 0, (size_t)Bb * NCP * sizeof(float2), stream);
    (void)hipMemsetAsync(wb0, 0, (size_t)Bb * KA * sizeof(__bf16), stream);
    (void)hipMemsetAsync(wb1, 0, (size_t)Bb * KA * sizeof(__bf16), stream);
    (void)hipMemsetAsync(Bp, 0, (size_t)JR * KB * sizeof(__bf16), stream);
    (void)hipMemsetAsync(slots, 0, 64 * sizeof(float), stream);

    // spectral norm chain on G (306x306): G -> normalize+square x KSQ -> Rayleigh
    gram_kernel<<<dim3(20, 20), dim3(16, 16), 0, stream>>>(pr, pi, G);
    float2* bufs[2] = { H1, H2 };
    const float2* src = G;
    for (int s = 0; s < KSQ; ++s) {
        frob_kernel<<<128, 256, 0, stream>>>(src, slots + s, Mm * Mm);
        float2* dst = bufs[s & 1];
        (void)hipMemsetAsync(dst, 0, (size_t)Mm * Mm * sizeof(float2), stream);
        sqmm_kernel<<<dim3(10, 10, 4), dim3(16, 16), 0, stream>>>(src, dst, slots + s);
        src = dst;
    }
    rayleigh_kernel<<<1, 320, 0, stream>>>(src, G, sc);

    // precompute packed operator (-step*Q, hi/lo) and step*rphi
    qpack_kernel<<<dim3(31, 31), 256, 0, stream>>>(pr, pi, (unsigned int*)Bp, sc);
    rphi_kernel<<<dim3(64, 16), 256, 0, stream>>>(rr, ri, pr, pi, rphis, sc);

    // ISTA main loop: one fused MFMA GEMM per iteration, w_bf16 ping-pong
    __bf16* wbuf[2] = { wb0, wb1 };
    for (int it = 0; it < ITERS; ++it) {
        ista4_kernel<<<dim3(32, 16), 256, 0, stream>>>(
            wbuf[it & 1], Bp, (unsigned int*)wbuf[(it + 1) & 1], w32, rphis, sc, out,
            it == ITERS - 1 ? 1 : 0);
    }
}